// Round 3
// baseline (1390.499 us; speedup 1.0000x reference)
//
#include <hip/hip_runtime.h>
#include <math.h>

// SGD filter design: 999 sequential gradient updates of a 16-section SOS
// (all sections provably identical -> compute one section), then emit
// pz_to_sos(params) replicated 16x. Single persistent 512-thread block,
// one frequency per thread, params lane-replicated in registers.

#define N_UPD 999
#define LRF   2e-5f
#define EPSF  1e-8f

__device__ __forceinline__ float rcp_(float x)  { return __builtin_amdgcn_rcpf(x); }
__device__ __forceinline__ float log2_(float x) { return __builtin_amdgcn_logf(x); }   // v_log_f32 (log2)
__device__ __forceinline__ float exp2_(float x) { return __builtin_amdgcn_exp2f(x); }  // v_exp_f32 (exp2)

__device__ __forceinline__ float tanh_pos(float u) {
    // tanh(u) for u >= 0:  1 - 2/(exp(2u)+1), exp via exp2
    float e = exp2_(u * 2.8853900817779268f); // 2/ln(2)
    return 1.0f - 2.0f * rcp_(e + 1.0f);
}

__global__ __launch_bounds__(512) void sgd_filter_kernel(const float* __restrict__ tgt,
                                                         float* __restrict__ out) {
    const int tid  = threadIdx.x;      // == frequency index, 0..511
    const int lane = tid & 63;
    const int wv   = tid >> 6;         // wave 0..7

    // per-frequency constants (live in registers for all iterations)
    const float w = (float)(3.14159265358979323846 * (double)tid / 511.0);
    float s1, c1;
    sincosf(w, &s1, &c1);
    const float c2 = c1 * c1 - s1 * s1;   // cos 2w  (matches e1*e1)
    const float s2 = 2.0f * c1 * s1;      // sin 2w
    const float tg = tgt[tid];

    // lane-replicated parameters (col 5 of sos is unused by the model)
    float q0  = 1.0f;                  // g = q0 + 1
    float qpr = 1.0f, qpi = 1.0f;      // raw pole
    float qzr = 1.0f, qzi = 1.0f;      // raw zero

    __shared__ float part[2][5][8];    // ping-pong cross-wave partials

    for (int it = 0; it < N_UPD; ++it) {
        // ---- uniform forward: params -> coefficients ----
        float g   = q0 + 1.0f;
        float pu  = sqrtf(qpr * qpr + qpi * qpi);
        float pt  = tanh_pos(pu);
        float psc = pt / pu;
        float prs = qpr * psc, pis = qpi * psc;
        float zu  = sqrtf(qzr * qzr + qzi * qzi);
        float zt  = tanh_pos(zu);
        float zsc = zt / zu;
        float zrs = qzr * zsc, zis = qzi * zsc;

        float b0 = g;
        float b1 = -2.0f * g * zrs;
        float zq = zrs * zrs + zis * zis;
        float b2 = g * zq;
        float a1 = -2.0f * prs;
        float a2 = prs * prs + pis * pis;

        // ---- per-frequency forward ----
        float Br = b0 + b1 * c1 + b2 * c2;
        float Bi = -(b1 * s1 + b2 * s2);
        float Ar = 1.0f + a1 * c1 + a2 * c2;
        float Ai = -(a1 * s1 + a2 * s2);
        float nb = Br * Br + Bi * Bi;
        float na = Ar * Ar + Ai * Ai;
        float lg = log2_(nb) - log2_(na);      // log2(|B|^2/|A|^2)
        float m  = exp2_(8.0f * lg);           // (|B|/|A|)^16 = |H|
        float mp = m + EPSF;
        float dB = 6.0205999132796239f * log2_(mp);   // 20*log10(m+eps)
        float err = dB - tg;
        // c = (2*err/512) * (20/ln10) * m/(m+eps)
        float cF = err * 0.033929256398692726f * m * rcp_(mp);

        // ---- per-frequency adjoint to coefficients ----
        float cb  = cF * rcp_(nb);
        float ca  = cF * rcp_(na);
        float gb0 = cb * Br;
        float gb1 = cb * (Br * c1 - Bi * s1);
        float gb2 = cb * (Br * c2 - Bi * s2);
        float ga1 = -ca * (Ar * c1 - Ai * s1);
        float ga2 = -ca * (Ar * c2 - Ai * s2);

        // ---- reduce the 5 gradient sums over 512 frequencies ----
        #pragma unroll
        for (int mk = 1; mk < 64; mk <<= 1) {
            gb0 += __shfl_xor(gb0, mk);
            gb1 += __shfl_xor(gb1, mk);
            gb2 += __shfl_xor(gb2, mk);
            ga1 += __shfl_xor(ga1, mk);
            ga2 += __shfl_xor(ga2, mk);
        }
        const int pp = it & 1;
        if (lane < 5) {
            float v = (lane == 0) ? gb0 : (lane == 1) ? gb1 : (lane == 2) ? gb2
                    : (lane == 3) ? ga1 : ga2;
            part[pp][lane][wv] = v;
        }
        __syncthreads();
        float S[5];
        #pragma unroll
        for (int l = 0; l < 5; ++l) {
            float4 u0 = *(const float4*)(&part[pp][l][0]);
            float4 u1 = *(const float4*)(&part[pp][l][4]);
            S[l] = ((u0.x + u0.y) + (u0.z + u0.w)) + ((u1.x + u1.y) + (u1.z + u1.w));
        }

        // ---- uniform backward: coefficients -> raw params ----
        float DB0 = S[0], DB1 = S[1], DB2 = S[2], DA1 = S[3], DA2 = S[4];
        float dg  = DB0 - 2.0f * zrs * DB1 + zq * DB2;
        float dzr = -2.0f * g * DB1 + 2.0f * g * zrs * DB2;
        float dzi = 2.0f * g * zis * DB2;
        float dpr = -2.0f * DA1 + 2.0f * prs * DA2;
        float dpi = 2.0f * pis * DA2;

        // tanh-normalization chain (z)
        float izu  = 1.0f / zu;
        float zds  = (1.0f - zt * zt) * izu - zt * izu * izu;  // d(scale)/du
        float zdot = qzr * dzr + qzi * dzi;
        float zcom = zds * izu * zdot;
        float gzr  = zsc * dzr + qzr * zcom;
        float gzi  = zsc * dzi + qzi * zcom;
        // tanh-normalization chain (p)
        float ipu  = 1.0f / pu;
        float pds  = (1.0f - pt * pt) * ipu - pt * ipu * ipu;
        float pdot = qpr * dpr + qpi * dpi;
        float pcom = pds * ipu * pdot;
        float gpr  = psc * dpr + qpr * pcom;
        float gpi  = psc * dpi + qpi * pcom;

        // SGD update (identical in every lane)
        q0  -= LRF * dg;
        qpr -= LRF * gpr;  qpi -= LRF * gpi;
        qzr -= LRF * gzr;  qzi -= LRF * gzi;
    }

    // ---- final pz_to_sos(params after 999 updates), 16 identical sections ----
    {
        float g   = q0 + 1.0f;
        float pu  = sqrtf(qpr * qpr + qpi * qpi);
        float psc = tanh_pos(pu) / pu;
        float prs = qpr * psc, pis = qpi * psc;
        float zu  = sqrtf(qzr * qzr + qzi * qzi);
        float zsc = tanh_pos(zu) / zu;
        float zrs = qzr * zsc, zis = qzi * zsc;
        float b0 = g;
        float b1 = -2.0f * g * zrs;
        float b2 = g * (zrs * zrs + zis * zis);
        float a1 = -2.0f * prs;
        float a2 = prs * prs + pis * pis;
        if (tid < 96) {
            int c = tid % 6;
            float v = (c == 0) ? b0 : (c == 1) ? b1 : (c == 2) ? b2
                    : (c == 3) ? 1.0f : (c == 4) ? a1 : a2;
            out[tid] = v;
        }
    }
}

extern "C" void kernel_launch(void* const* d_in, const int* in_sizes, int n_in,
                              void* d_out, int out_size, void* d_ws, size_t ws_size,
                              hipStream_t stream) {
    (void)in_sizes; (void)n_in; (void)d_ws; (void)ws_size; (void)out_size;
    const float* tgt = (const float*)d_in[0];
    float* out = (float*)d_out;
    hipLaunchKernelGGL(sgd_filter_kernel, dim3(1), dim3(512), 0, stream, tgt, out);
}

// Round 7
// 708.252 us; speedup vs baseline: 1.9633x; 1.9633x over previous
//
#include <hip/hip_runtime.h>
#include <math.h>

// SGD filter design: 999 sequential SGD steps on one SOS section (all 16
// provably identical), persistent single block, 256 threads (4 waves),
// 2 frequencies per lane. Reductions via DPP (VALU-speed) instead of
// ds_bpermute shuffles; one ds_read_b32 + barrier per iteration.

#define N_UPD 999
#define LRF   2e-5f
#define EPSF  1e-8f

__device__ __forceinline__ float rcp_(float x)  { return __builtin_amdgcn_rcpf(x); }
__device__ __forceinline__ float log2_(float x) { return __builtin_amdgcn_logf(x); }   // v_log_f32
__device__ __forceinline__ float exp2_(float x) { return __builtin_amdgcn_exp2f(x); }  // v_exp_f32

__device__ __forceinline__ float tanh_pos(float u) {
    float e = exp2_(u * 2.8853900817779268f); // exp(2u) via exp2
    return 1.0f - 2.0f * rcp_(e + 1.0f);
}

// x += dpp_perm(x); invalid source lanes contribute 0 (bound_ctrl=true).
// CTRL must be an immediate -> template parameter.
template <int CTRL>
__device__ __forceinline__ float dpp_add(float x) {
    int y = __builtin_amdgcn_update_dpp(0, __float_as_int(x), CTRL, 0xF, 0xF, true);
    return x + __int_as_float(y);
}

// Full 64-lane sum; result valid at lane 63 (classic GCN DPP reduction).
__device__ __forceinline__ float wave_sum_at63(float x) {
    x = dpp_add<0x111>(x);  // row_shr:1
    x = dpp_add<0x112>(x);  // row_shr:2
    x = dpp_add<0x114>(x);  // row_shr:4
    x = dpp_add<0x118>(x);  // row_shr:8   -> lanes 15/31/47/63 = row sums
    x = dpp_add<0x142>(x);  // row_bcast:15 -> lane31 += lane15, lane63 += lane47
    x = dpp_add<0x143>(x);  // row_bcast:31 -> lane63 = total
    return x;
}

__device__ __forceinline__ float readlane_f(float x, int l) {
    return __int_as_float(__builtin_amdgcn_readlane(__float_as_int(x), l));
}

__global__ __launch_bounds__(256) void sgd_filter_kernel(const float* __restrict__ tgt,
                                                         float* __restrict__ out) {
    const int tid  = threadIdx.x;      // 0..255
    const int lane = tid & 63;
    const int wv   = tid >> 6;         // wave 0..3

    // two frequencies per lane: f0 = tid, f1 = tid + 256
    const float wA = (float)(3.14159265358979323846 * (double)tid / 511.0);
    const float wB = (float)(3.14159265358979323846 * (double)(tid + 256) / 511.0);
    float s1a, c1a, s1b, c1b;
    sincosf(wA, &s1a, &c1a);
    sincosf(wB, &s1b, &c1b);
    const float c2a = c1a * c1a - s1a * s1a, s2a = 2.0f * c1a * s1a;
    const float c2b = c1b * c1b - s1b * s1b, s2b = 2.0f * c1b * s1b;
    const float tga = tgt[tid];
    const float tgb = tgt[tid + 256];

    // lane-replicated parameters
    float q0  = 1.0f;
    float qpr = 1.0f, qpi = 1.0f;
    float qzr = 1.0f, qzi = 1.0f;

    __shared__ float part[2][32];      // ping-pong; idx = l*4 + wave (l=0..4)

    for (int it = 0; it < N_UPD; ++it) {
        // ---- uniform forward: params -> coefficients ----
        float g   = q0 + 1.0f;
        float pu  = sqrtf(qpr * qpr + qpi * qpi);
        float pt  = tanh_pos(pu);
        float psc = pt / pu;
        float prs = qpr * psc, pis = qpi * psc;
        float zu  = sqrtf(qzr * qzr + qzi * qzi);
        float zt  = tanh_pos(zu);
        float zsc = zt / zu;
        float zrs = qzr * zsc, zis = qzi * zsc;

        float b0 = g;
        float b1 = -2.0f * g * zrs;
        float zq = zrs * zrs + zis * zis;
        float b2 = g * zq;
        float a1 = -2.0f * prs;
        float a2 = prs * prs + pis * pis;

        // ---- per-frequency forward + adjoint, 2 freqs/lane ----
        float gb0 = 0.0f, gb1 = 0.0f, gb2 = 0.0f, ga1 = 0.0f, ga2 = 0.0f;
#define PERFREQ(C1, S1, C2, S2, TG)                                   \
        {                                                             \
            float Br = b0 + b1 * C1 + b2 * C2;                        \
            float Bi = -(b1 * S1 + b2 * S2);                          \
            float Ar = 1.0f + a1 * C1 + a2 * C2;                      \
            float Ai = -(a1 * S1 + a2 * S2);                          \
            float nb = Br * Br + Bi * Bi;                             \
            float na = Ar * Ar + Ai * Ai;                             \
            float m  = exp2_(8.0f * (log2_(nb) - log2_(na)));         \
            float mp = m + EPSF;                                      \
            float dB = 6.0205999132796239f * log2_(mp);               \
            float cF = (dB - TG) * 0.033929256398692726f * m * rcp_(mp); \
            float cb = cF * rcp_(nb);                                 \
            float ca = cF * rcp_(na);                                 \
            gb0 += cb * Br;                                           \
            gb1 += cb * (Br * C1 - Bi * S1);                          \
            gb2 += cb * (Br * C2 - Bi * S2);                          \
            ga1 -= ca * (Ar * C1 - Ai * S1);                          \
            ga2 -= ca * (Ar * C2 - Ai * S2);                          \
        }
        PERFREQ(c1a, s1a, c2a, s2a, tga)
        PERFREQ(c1b, s1b, c2b, s2b, tgb)
#undef PERFREQ

        // ---- in-wave sum via DPP (valid at lane 63) ----
        float t0 = wave_sum_at63(gb0);
        float t1 = wave_sum_at63(gb1);
        float t2 = wave_sum_at63(gb2);
        float t3 = wave_sum_at63(ga1);
        float t4 = wave_sum_at63(ga2);

        const int pp = it & 1;
        if (lane == 63) {
            float* pb = &part[pp][0];
            pb[ 0 + wv] = t0;
            pb[ 4 + wv] = t1;
            pb[ 8 + wv] = t2;
            pb[12 + wv] = t3;
            pb[16 + wv] = t4;
        }
        __syncthreads();

        // ---- cross-wave: lanes 0..19 hold the 5x4 partials ----
        float y = part[pp][lane & 31];
        y = dpp_add<0x111>(y);   // group-of-4 partial sums ...
        y = dpp_add<0x112>(y);   // ... complete at lanes 3,7,11,15,19
        float S0 = readlane_f(y, 3);
        float S1 = readlane_f(y, 7);
        float S2 = readlane_f(y, 11);
        float S3 = readlane_f(y, 15);
        float S4 = readlane_f(y, 19);

        // ---- uniform backward: coefficients -> raw params ----
        float dg  = S0 - 2.0f * zrs * S1 + zq * S2;
        float dzr = -2.0f * g * S1 + 2.0f * g * zrs * S2;
        float dzi = 2.0f * g * zis * S2;
        float dpr = -2.0f * S3 + 2.0f * prs * S4;
        float dpi = 2.0f * pis * S4;

        float izu  = 1.0f / zu;
        float zds  = (1.0f - zt * zt) * izu - zt * izu * izu;
        float zdot = qzr * dzr + qzi * dzi;
        float zcom = zds * izu * zdot;
        float gzr  = zsc * dzr + qzr * zcom;
        float gzi  = zsc * dzi + qzi * zcom;

        float ipu  = 1.0f / pu;
        float pds  = (1.0f - pt * pt) * ipu - pt * ipu * ipu;
        float pdot = qpr * dpr + qpi * dpi;
        float pcom = pds * ipu * pdot;
        float gpr  = psc * dpr + qpr * pcom;
        float gpi  = psc * dpi + qpi * pcom;

        q0  -= LRF * dg;
        qpr -= LRF * gpr;  qpi -= LRF * gpi;
        qzr -= LRF * gzr;  qzi -= LRF * gzi;
    }

    // ---- final pz_to_sos, 16 identical sections ----
    {
        float g   = q0 + 1.0f;
        float pu  = sqrtf(qpr * qpr + qpi * qpi);
        float psc = tanh_pos(pu) / pu;
        float prs = qpr * psc, pis = qpi * psc;
        float zu  = sqrtf(qzr * qzr + qzi * qzi);
        float zsc = tanh_pos(zu) / zu;
        float zrs = qzr * zsc, zis = qzi * zsc;
        float b0 = g;
        float b1 = -2.0f * g * zrs;
        float b2 = g * (zrs * zrs + zis * zis);
        float a1 = -2.0f * prs;
        float a2 = prs * prs + pis * pis;
        if (tid < 96) {
            int c = tid % 6;
            float v = (c == 0) ? b0 : (c == 1) ? b1 : (c == 2) ? b2
                    : (c == 3) ? 1.0f : (c == 4) ? a1 : a2;
            out[tid] = v;
        }
    }
}

extern "C" void kernel_launch(void* const* d_in, const int* in_sizes, int n_in,
                              void* d_out, int out_size, void* d_ws, size_t ws_size,
                              hipStream_t stream) {
    (void)in_sizes; (void)n_in; (void)d_ws; (void)ws_size; (void)out_size;
    const float* tgt = (const float*)d_in[0];
    float* out = (float*)d_out;
    hipLaunchKernelGGL(sgd_filter_kernel, dim3(1), dim3(256), 0, stream, tgt, out);
}

// Round 9
// 557.847 us; speedup vs baseline: 2.4926x; 1.2696x over previous
//
#include <hip/hip_runtime.h>
#include <math.h>

// SGD filter design: 999 sequential SGD steps on one SOS section (all 16
// provably identical), persistent single block, 256 threads (4 waves),
// 2 frequencies per lane. DPP reductions; one ds_read_b32 + barrier per
// iteration. Round 8: all IEEE divides/sqrt -> v_rcp/v_sqrt, reciprocals
// reused, one log2 folded, constants folded.

#define N_UPD 999
#define LRF   2e-5f
#define EPSF  1e-8f

__device__ __forceinline__ float rcp_(float x)  { return __builtin_amdgcn_rcpf(x); }
__device__ __forceinline__ float sqrt_(float x) { return __builtin_amdgcn_sqrtf(x); }
__device__ __forceinline__ float log2_(float x) { return __builtin_amdgcn_logf(x); }   // v_log_f32
__device__ __forceinline__ float exp2_(float x) { return __builtin_amdgcn_exp2f(x); }  // v_exp_f32

// tanh(u) for u >= 0:  1 - 2/(exp(2u)+1)
__device__ __forceinline__ float tanh_pos(float u) {
    float e = exp2_(u * 2.8853900817779268f); // 2/ln2
    return 1.0f - 2.0f * rcp_(e + 1.0f);
}

// x += dpp_perm(x); invalid source lanes contribute 0 (bound_ctrl=true).
template <int CTRL>
__device__ __forceinline__ float dpp_add(float x) {
    int y = __builtin_amdgcn_update_dpp(0, __float_as_int(x), CTRL, 0xF, 0xF, true);
    return x + __int_as_float(y);
}

// Full 64-lane sum; result valid at lane 63.
__device__ __forceinline__ float wave_sum_at63(float x) {
    x = dpp_add<0x111>(x);  // row_shr:1
    x = dpp_add<0x112>(x);  // row_shr:2
    x = dpp_add<0x114>(x);  // row_shr:4
    x = dpp_add<0x118>(x);  // row_shr:8
    x = dpp_add<0x142>(x);  // row_bcast:15
    x = dpp_add<0x143>(x);  // row_bcast:31 -> lane63 = total
    return x;
}

__device__ __forceinline__ float readlane_f(float x, int l) {
    return __int_as_float(__builtin_amdgcn_readlane(__float_as_int(x), l));
}

// dB = K*log2(mp);  err*C = K*C*(log2(mp) - tg/K)
#define KC_   0.20427448f        // K*C = 6.0205999132796 * 0.03392925639869
#define INVK_ 0.16609640474436813f

__global__ __launch_bounds__(256) void sgd_filter_kernel(const float* __restrict__ tgt,
                                                         float* __restrict__ out) {
    const int tid  = threadIdx.x;      // 0..255
    const int lane = tid & 63;
    const int wv   = tid >> 6;         // wave 0..3

    // two frequencies per lane: f0 = tid, f1 = tid + 256
    const float wA = (float)(3.14159265358979323846 * (double)tid / 511.0);
    const float wB = (float)(3.14159265358979323846 * (double)(tid + 256) / 511.0);
    float s1a, c1a, s1b, c1b;
    sincosf(wA, &s1a, &c1a);
    sincosf(wB, &s1b, &c1b);
    const float c2a = c1a * c1a - s1a * s1a, s2a = 2.0f * c1a * s1a;
    const float c2b = c1b * c1b - s1b * s1b, s2b = 2.0f * c1b * s1b;
    const float tka = tgt[tid] * INVK_;        // tg / K, pre-folded
    const float tkb = tgt[tid + 256] * INVK_;

    // lane-replicated parameters
    float q0  = 1.0f;
    float qpr = 1.0f, qpi = 1.0f;
    float qzr = 1.0f, qzi = 1.0f;

    __shared__ float part[2][32];      // ping-pong; idx = l*4 + wave (l=0..4)

    for (int it = 0; it < N_UPD; ++it) {
        // ---- uniform forward: params -> coefficients (rcp reused) ----
        float g   = q0 + 1.0f;
        float pu  = sqrt_(qpr * qpr + qpi * qpi);
        float ipu = rcp_(pu);
        float tp  = tanh_pos(pu);
        float psc = tp * ipu;
        float prs = qpr * psc, pis = qpi * psc;

        float zu  = sqrt_(qzr * qzr + qzi * qzi);
        float izu = rcp_(zu);
        float tz  = tanh_pos(zu);
        float zsc = tz * izu;
        float zrs = qzr * zsc, zis = qzi * zsc;

        float b0 = g;
        float b1 = -2.0f * g * zrs;
        float zq = tz * tz;            // = zrs^2 + zis^2
        float b2 = g * zq;
        float a1 = -2.0f * prs;
        float a2 = tp * tp;            // = prs^2 + pis^2

        // ---- per-frequency forward + adjoint, 2 freqs/lane ----
        float gb0 = 0.0f, gb1 = 0.0f, gb2 = 0.0f, ga1 = 0.0f, ga2 = 0.0f;
#define PERFREQ(C1, S1, C2, S2, TGK)                                  \
        {                                                             \
            float Br = b0 + b1 * C1 + b2 * C2;                        \
            float Bi = -(b1 * S1 + b2 * S2);                          \
            float Ar = 1.0f + a1 * C1 + a2 * C2;                      \
            float Ai = -(a1 * S1 + a2 * S2);                          \
            float nb = Br * Br + Bi * Bi;                             \
            float na = Ar * Ar + Ai * Ai;                             \
            float rnb = rcp_(nb);                                     \
            float rna = rcp_(na);                                     \
            float m  = exp2_(8.0f * log2_(nb * rna));                 \
            float mp = m + EPSF;                                      \
            float cF = KC_ * (log2_(mp) - TGK) * m * rcp_(mp);        \
            float cb = cF * rnb;                                      \
            float ca = cF * rna;                                      \
            float cbBr = cb * Br, cbBi = cb * Bi;                     \
            float caAr = ca * Ar, caAi = ca * Ai;                     \
            gb0 += cbBr;                                              \
            gb1 += cbBr * C1 - cbBi * S1;                             \
            gb2 += cbBr * C2 - cbBi * S2;                             \
            ga1 -= caAr * C1 - caAi * S1;                             \
            ga2 -= caAr * C2 - caAi * S2;                             \
        }
        PERFREQ(c1a, s1a, c2a, s2a, tka)
        PERFREQ(c1b, s1b, c2b, s2b, tkb)
#undef PERFREQ

        // ---- in-wave sum via DPP (valid at lane 63) ----
        float t0 = wave_sum_at63(gb0);
        float t1 = wave_sum_at63(gb1);
        float t2 = wave_sum_at63(gb2);
        float t3 = wave_sum_at63(ga1);
        float t4 = wave_sum_at63(ga2);

        const int pp = it & 1;
        if (lane == 63) {
            float* pb = &part[pp][0];
            pb[ 0 + wv] = t0;
            pb[ 4 + wv] = t1;
            pb[ 8 + wv] = t2;
            pb[12 + wv] = t3;
            pb[16 + wv] = t4;
        }
        __syncthreads();

        // ---- cross-wave: lanes 0..19 hold the 5x4 partials ----
        float y = part[pp][lane & 31];
        y = dpp_add<0x111>(y);   // group-of-4 partial sums ...
        y = dpp_add<0x112>(y);   // ... complete at lanes 3,7,11,15,19
        float S0 = readlane_f(y, 3);
        float S1 = readlane_f(y, 7);
        float S2 = readlane_f(y, 11);
        float S3 = readlane_f(y, 15);
        float S4 = readlane_f(y, 19);

        // ---- uniform backward: coefficients -> raw params ----
        float dg  = S0 - 2.0f * zrs * S1 + zq * S2;
        float dzr = 2.0f * g * (zrs * S2 - S1);
        float dzi = 2.0f * g * zis * S2;
        float dpr = 2.0f * (prs * S4 - S3);
        float dpi = 2.0f * pis * S4;

        // tanh-normalization chain (z): zds = ((1-tz^2) - tz*izu) * izu
        float zds  = ((1.0f - zq) - tz * izu) * izu;
        float zdot = qzr * dzr + qzi * dzi;
        float zcom = zds * izu * zdot;
        float gzr  = zsc * dzr + qzr * zcom;
        float gzi  = zsc * dzi + qzi * zcom;

        float pds  = ((1.0f - a2) - tp * ipu) * ipu;
        float pdot = qpr * dpr + qpi * dpi;
        float pcom = pds * ipu * pdot;
        float gpr  = psc * dpr + qpr * pcom;
        float gpi  = psc * dpi + qpi * pcom;

        q0  -= LRF * dg;
        qpr -= LRF * gpr;  qpi -= LRF * gpi;
        qzr -= LRF * gzr;  qzi -= LRF * gzi;
    }

    // ---- final pz_to_sos, 16 identical sections ----
    {
        float g   = q0 + 1.0f;
        float pu  = sqrt_(qpr * qpr + qpi * qpi);
        float psc = tanh_pos(pu) * rcp_(pu);
        float prs = qpr * psc, pis = qpi * psc;
        float zu  = sqrt_(qzr * qzr + qzi * qzi);
        float zsc = tanh_pos(zu) * rcp_(zu);
        float zrs = qzr * zsc, zis = qzi * zsc;
        float b0 = g;
        float b1 = -2.0f * g * zrs;
        float b2 = g * (zrs * zrs + zis * zis);
        float a1 = -2.0f * prs;
        float a2 = prs * prs + pis * pis;
        if (tid < 96) {
            int c = tid % 6;
            float v = (c == 0) ? b0 : (c == 1) ? b1 : (c == 2) ? b2
                    : (c == 3) ? 1.0f : (c == 4) ? a1 : a2;
            out[tid] = v;
        }
    }
}

extern "C" void kernel_launch(void* const* d_in, const int* in_sizes, int n_in,
                              void* d_out, int out_size, void* d_ws, size_t ws_size,
                              hipStream_t stream) {
    (void)in_sizes; (void)n_in; (void)d_ws; (void)ws_size; (void)out_size;
    const float* tgt = (const float*)d_in[0];
    float* out = (float*)d_out;
    hipLaunchKernelGGL(sgd_filter_kernel, dim3(1), dim3(256), 0, stream, tgt, out);
}